// Round 4
// baseline (597.139 us; speedup 1.0000x reference)
//
#include <hip/hip_runtime.h>
#include <hip/hip_bf16.h>

#define N_NODES 100000
#define DEGREE 32
#define N_PAIRS 8192
#define FEAT 9
#define HID 20
#define NOUT 15

#define NPB 28                              // nodes per node-block (28*9=252 lanes)
#define PPB 8                               // pairs per pair-block (8*30=240 lanes)
#define GRID_NODE ((N_NODES + NPB - 1) / NPB)   // 3572
#define GRID_PAIR (N_PAIRS / PPB)               // 1024

// ---------------------------------------------------------------------------
// Single fused kernel.
//   Blocks [0, GRID_NODE): enc1+enc2-inner per node -> t (bf16) + release-add
//     on a device-scope counter.
//   Blocks [GRID_NODE, GRID_NODE+GRID_PAIR): stage MLP weights in LDS, spin-
//     acquire on the counter until all node blocks are done, then endpoint
//     aggregation + pair MLP -> out.
//   Deadlock-safe: 1024 spinner blocks < 2048 co-resident block capacity
//     (256 thr/block, 2048 thr/CU, LDS 6.9 KB/block), so node blocks always
//     have CU slots to flow through.
// ---------------------------------------------------------------------------
__global__ __launch_bounds__(256) void k_fused(
    const int* __restrict__ to_pred,
    const int* __restrict__ adj,
    const float* __restrict__ feat,
    const float* __restrict__ W1,     // [HID][2*FEAT]
    const float* __restrict__ W2,     // [NOUT][HID]
    const float* __restrict__ fc1_w,  // [15][30]
    const float* __restrict__ fc1_b,  // [15]
    const float* __restrict__ fc2_w,  // [1][15]
    const float* __restrict__ fc2_b,  // [1]
    __hip_bfloat16* __restrict__ t_ws,
    unsigned int* __restrict__ counter,
    float* __restrict__ out) {
  // union'd LDS: node path needs 1724 floats, pair path 841.
  __shared__ float smem[1724];
  int tid = threadIdx.x;
  int bid = blockIdx.x;

  if (bid < GRID_NODE) {
    // ---------------- node path ----------------
    float* sW1 = smem;                 // 360
    float* sW2 = smem + 360;           // 300
    float* sComb = smem + 660;         // NPB*18 = 504
    float* sH = smem + 1164;           // NPB*20 = 560

    for (int i = tid; i < HID * 2 * FEAT; i += 256) sW1[i] = W1[i];
    for (int i = tid; i < NOUT * HID; i += 256) sW2[i] = W2[i];

    int base = bid * NPB;

    // phase 1: [self feat | neighbor mean] -> sComb
    if (tid < NPB * FEAT) {
      int nl = tid / FEAT;
      int j = tid - nl * FEAT;
      int n = base + nl;
      if (n < N_NODES) {
        const int* arow = adj + n * DEGREE;
        float s = 0.f;
#pragma unroll
        for (int k = 0; k < DEGREE; ++k) {
          int m = arow[k];
          s += feat[m * FEAT + j];
        }
        sComb[nl * 18 + j] = feat[n * FEAT + j];
        sComb[nl * 18 + FEAT + j] = s * (1.0f / DEGREE);
      }
    }
    __syncthreads();

    // phase 2: h1 = relu(W1 @ comb)
    for (int idx = tid; idx < NPB * HID; idx += 256) {
      int nl = idx / HID;
      int i = idx - nl * HID;
      if (base + nl < N_NODES) {
        float acc = 0.f;
#pragma unroll
        for (int j = 0; j < 2 * FEAT; ++j)
          acc += sW1[i * 2 * FEAT + j] * sComb[nl * 18 + j];
        sH[nl * HID + i] = fmaxf(acc, 0.f);
      }
    }
    __syncthreads();

    // phase 3: t = W2 @ h1 (linear; relu is applied after the enc2 mean)
    for (int idx = tid; idx < NPB * NOUT; idx += 256) {
      int nl = idx / NOUT;
      int d = idx - nl * NOUT;
      int n = base + nl;
      if (n < N_NODES) {
        float acc = 0.f;
#pragma unroll
        for (int i = 0; i < HID; ++i) acc += sW2[d * HID + i] * sH[nl * HID + i];
        t_ws[n * NOUT + d] = __float2bfloat16(acc);
      }
    }

    // make t visible at agent scope, then signal
    __threadfence();
    __syncthreads();
    if (tid == 0)
      __hip_atomic_fetch_add(counter, 1u, __ATOMIC_RELEASE,
                             __HIP_MEMORY_SCOPE_AGENT);
  } else {
    // ---------------- pair path ----------------
    float* s1 = smem;                  // 450
    float* b1v = smem + 450;           // 15
    float* s2v = smem + 465;           // 15
    float* b2v = smem + 480;           // 1
    float* sE = smem + 481;            // PPB*30 = 240
    float* sHh = smem + 721;           // PPB*15 = 120

    // stage weights while node blocks run
    for (int i = tid; i < 15 * 30; i += 256) s1[i] = fc1_w[i];
    if (tid < 15) {
      b1v[tid] = fc1_b[tid];
      s2v[tid] = fc2_w[tid];
    }
    if (tid == 0) *b2v = fc2_b[0];

    // wait for all node blocks (acquire)
    if (tid == 0) {
      while (__hip_atomic_load(counter, __ATOMIC_ACQUIRE,
                               __HIP_MEMORY_SCOPE_AGENT) < (unsigned)GRID_NODE)
        __builtin_amdgcn_s_sleep(16);
    }
    __syncthreads();
    __threadfence();

    int pbase = (bid - GRID_NODE) * PPB;

    // phase 1: e = relu(mean over {self, 32 neighbors} of t)
    if (tid < PPB * 30) {
      int pl = tid / 30;
      int slot = tid - pl * 30;
      int side = slot / 15;
      int d = slot - side * 15;
      int p = pbase + pl;
      int node = to_pred[2 * p + side];
      const int* arow = adj + node * DEGREE;
      float s = __bfloat162float(t_ws[node * NOUT + d]);  // gcn=True self term
#pragma unroll
      for (int k = 0; k < DEGREE; ++k) {
        int m = arow[k];
        s += __bfloat162float(t_ws[m * NOUT + d]);
      }
      sE[pl * 30 + slot] = fmaxf(s * (1.0f / (DEGREE + 1)), 0.f);
    }
    __syncthreads();

    // phase 2: h = relu(fc1 @ e + b1)
    if (tid < PPB * 15) {
      int pl = tid / 15;
      int i = tid - pl * 15;
      float acc = b1v[i];
#pragma unroll
      for (int j = 0; j < 30; ++j) acc += s1[i * 30 + j] * sE[pl * 30 + j];
      sHh[pl * 15 + i] = fmaxf(acc, 0.f);
    }
    __syncthreads();

    // phase 3: out = relu(fc2 @ h + b2)
    if (tid < PPB) {
      float acc = *b2v;
#pragma unroll
      for (int i = 0; i < 15; ++i) acc += s2v[i] * sHh[tid * 15 + i];
      out[pbase + tid] = fmaxf(acc, 0.f);
    }
  }
}

// ---------------------------------------------------------------------------
extern "C" void kernel_launch(void* const* d_in, const int* in_sizes, int n_in,
                              void* d_out, int out_size, void* d_ws,
                              size_t ws_size, hipStream_t stream) {
  const int* to_pred = (const int*)d_in[0];
  const int* adj     = (const int*)d_in[1];
  const float* feat  = (const float*)d_in[2];
  const float* W1    = (const float*)d_in[3];
  const float* W2    = (const float*)d_in[4];
  const float* fc1_w = (const float*)d_in[5];
  const float* fc1_b = (const float*)d_in[6];
  const float* fc2_w = (const float*)d_in[7];
  const float* fc2_b = (const float*)d_in[8];
  float* out         = (float*)d_out;

  char* ws = (char*)d_ws;
  __hip_bfloat16* t_ws = (__hip_bfloat16*)ws;          // 100000*15*2 = 3,000,000 B
  unsigned int* counter = (unsigned int*)(ws + 3000000);

  // zero the completion counter (ws is re-poisoned to 0xAA before every call)
  hipMemsetAsync(counter, 0, sizeof(unsigned int), stream);

  k_fused<<<GRID_NODE + GRID_PAIR, 256, 0, stream>>>(
      to_pred, adj, feat, W1, W2, fc1_w, fc1_b, fc2_w, fc2_b, t_ws, counter,
      out);
}

// Round 5
// 116.206 us; speedup vs baseline: 5.1386x; 5.1386x over previous
//
#include <hip/hip_runtime.h>
#include <hip/hip_bf16.h>

#define N_NODES 100000
#define DEGREE 32
#define N_PAIRS 8192
#define FEAT 9
#define HID 20
#define NOUT 15

#define NPB 28   // nodes per block in K1 (28*9 = 252 active lanes of 256)
#define PPB 8    // pairs per block in K2 (8*30 = 240 active lanes of 256)

// ---------------------------------------------------------------------------
// K1: fused enc1-mean + node MLP. t stored bf16 (validated: absmax 6.1e-5).
//   phase 1: thread (node, j): adj row via 8x int4 (broadcast within the
//            9-lane group), 32 scattered 36B feat-row gathers -> sComb in LDS.
//   phase 2: (node, i): h1[i] = relu(W1[i] . comb)
//   phase 3: (node, d): t[n,d] = W2[d] . h1   (linear; relu comes after the
//            enc2 mean) -> global t_ws (bf16).
// ---------------------------------------------------------------------------
__global__ __launch_bounds__(256) void k_node_all(
    const int* __restrict__ adj,
    const float* __restrict__ feat,
    const float* __restrict__ W1,   // [HID][2*FEAT]
    const float* __restrict__ W2,   // [NOUT][HID]
    __hip_bfloat16* __restrict__ t_ws) {
  __shared__ float sW1[HID * 2 * FEAT];   // 360
  __shared__ float sW2[NOUT * HID];       // 300
  __shared__ float sComb[NPB][2 * FEAT];  // 28 x 18
  __shared__ float sH[NPB][HID];          // 28 x 20

  int tid = threadIdx.x;
  for (int i = tid; i < HID * 2 * FEAT; i += 256) sW1[i] = W1[i];
  for (int i = tid; i < NOUT * HID; i += 256) sW2[i] = W2[i];

  int base = blockIdx.x * NPB;

  // phase 1: [self feat | neighbor mean] -> sComb
  if (tid < NPB * FEAT) {
    int nl = tid / FEAT;
    int j = tid - nl * FEAT;
    int n = base + nl;
    if (n < N_NODES) {
      const int4* arow4 = (const int4*)(adj + n * DEGREE);  // 128B-aligned
      float s = 0.f;
#pragma unroll
      for (int c = 0; c < DEGREE / 4; ++c) {
        int4 a4 = arow4[c];
        s += feat[a4.x * FEAT + j];
        s += feat[a4.y * FEAT + j];
        s += feat[a4.z * FEAT + j];
        s += feat[a4.w * FEAT + j];
      }
      sComb[nl][j] = feat[n * FEAT + j];
      sComb[nl][FEAT + j] = s * (1.0f / DEGREE);
    }
  }
  __syncthreads();

  // phase 2: h1 = relu(W1 @ comb), one thread per (node, hid)
  for (int idx = tid; idx < NPB * HID; idx += 256) {
    int nl = idx / HID;
    int i = idx - nl * HID;
    if (base + nl < N_NODES) {
      float acc = 0.f;
#pragma unroll
      for (int j = 0; j < 2 * FEAT; ++j) acc += sW1[i * 2 * FEAT + j] * sComb[nl][j];
      sH[nl][i] = fmaxf(acc, 0.f);
    }
  }
  __syncthreads();

  // phase 3: t = W2 @ h1 (linear), one thread per (node, out)
  for (int idx = tid; idx < NPB * NOUT; idx += 256) {
    int nl = idx / NOUT;
    int d = idx - nl * NOUT;
    int n = base + nl;
    if (n < N_NODES) {
      float acc = 0.f;
#pragma unroll
      for (int i = 0; i < HID; ++i) acc += sW2[d * HID + i] * sH[nl][i];
      t_ws[n * NOUT + d] = __float2bfloat16(acc);
    }
  }
}

// ---------------------------------------------------------------------------
// K2: fused enc2 endpoint aggregation + pair MLP. t read as bf16 (30B rows).
//   phase 1: thread (pair, side, d) gathers 33 t-values -> e = relu(mean) in
//            LDS, concat order [side0 | side1].
//   phase 2: (pair, i): h[i] = relu(fc1[i] . e + b1[i])
//   phase 3: (pair): out = relu(fc2 . h + b2) -> global (fp32).
// ---------------------------------------------------------------------------
__global__ __launch_bounds__(256) void k_pair_all(
    const int* __restrict__ to_pred,
    const int* __restrict__ adj,
    const __hip_bfloat16* __restrict__ t_ws,
    const float* __restrict__ fc1_w,  // [15][30]
    const float* __restrict__ fc1_b,  // [15]
    const float* __restrict__ fc2_w,  // [1][15]
    const float* __restrict__ fc2_b,  // [1]
    float* __restrict__ out) {
  __shared__ float s1[15 * 30];
  __shared__ float b1v[15];
  __shared__ float s2v[15];
  __shared__ float b2v;
  __shared__ float sE[PPB][30];
  __shared__ float sHh[PPB][15];

  int tid = threadIdx.x;
  for (int i = tid; i < 15 * 30; i += 256) s1[i] = fc1_w[i];
  if (tid < 15) {
    b1v[tid] = fc1_b[tid];
    s2v[tid] = fc2_w[tid];
  }
  if (tid == 0) b2v = fc2_b[0];

  int pbase = blockIdx.x * PPB;

  // phase 1: endpoint aggregate (self + 32 neighbors of t, then relu(mean))
  if (tid < PPB * 30) {
    int pl = tid / 30;
    int slot = tid - pl * 30;
    int side = slot / 15;
    int d = slot - side * 15;
    int p = pbase + pl;                 // N_PAIRS % PPB == 0, always in range
    int node = to_pred[2 * p + side];
    const int4* arow4 = (const int4*)(adj + node * DEGREE);
    float s = __bfloat162float(t_ws[node * NOUT + d]);  // gcn=True self term
#pragma unroll
    for (int c = 0; c < DEGREE / 4; ++c) {
      int4 a4 = arow4[c];
      s += __bfloat162float(t_ws[a4.x * NOUT + d]);
      s += __bfloat162float(t_ws[a4.y * NOUT + d]);
      s += __bfloat162float(t_ws[a4.z * NOUT + d]);
      s += __bfloat162float(t_ws[a4.w * NOUT + d]);
    }
    sE[pl][slot] = fmaxf(s * (1.0f / (DEGREE + 1)), 0.f);
  }
  __syncthreads();

  // phase 2: h = relu(fc1 @ e + b1), one thread per (pair, i)
  if (tid < PPB * 15) {
    int pl = tid / 15;
    int i = tid - pl * 15;
    float acc = b1v[i];
#pragma unroll
    for (int j = 0; j < 30; ++j) acc += s1[i * 30 + j] * sE[pl][j];
    sHh[pl][i] = fmaxf(acc, 0.f);
  }
  __syncthreads();

  // phase 3: out = relu(fc2 @ h + b2), one thread per pair
  if (tid < PPB) {
    float acc = b2v;
#pragma unroll
    for (int i = 0; i < 15; ++i) acc += s2v[i] * sHh[tid][i];
    out[pbase + tid] = fmaxf(acc, 0.f);
  }
}

// ---------------------------------------------------------------------------
extern "C" void kernel_launch(void* const* d_in, const int* in_sizes, int n_in,
                              void* d_out, int out_size, void* d_ws,
                              size_t ws_size, hipStream_t stream) {
  const int* to_pred = (const int*)d_in[0];
  const int* adj     = (const int*)d_in[1];
  const float* feat  = (const float*)d_in[2];
  const float* W1    = (const float*)d_in[3];
  const float* W2    = (const float*)d_in[4];
  const float* fc1_w = (const float*)d_in[5];
  const float* fc1_b = (const float*)d_in[6];
  const float* fc2_w = (const float*)d_in[7];
  const float* fc2_b = (const float*)d_in[8];
  float* out         = (float*)d_out;

  __hip_bfloat16* t_ws = (__hip_bfloat16*)d_ws;  // 100000*15*2 = 3 MB

  int grid1 = (N_NODES + NPB - 1) / NPB;   // 3572
  k_node_all<<<grid1, 256, 0, stream>>>(adj, feat, W1, W2, t_ws);

  int grid2 = N_PAIRS / PPB;               // 1024
  k_pair_all<<<grid2, 256, 0, stream>>>(to_pred, adj, t_ws, fc1_w, fc1_b,
                                        fc2_w, fc2_b, out);
}